// Round 9
// baseline (123.484 us; speedup 1.0000x reference)
//
#include <hip/hip_runtime.h>
#include <cstdint>

// CapsuleLayer dynamic routing: B=256, R=1152, C=10, O=16, I=8, 3 iters.
// Round 9: u NEVER touches LDS — register-resident end-to-end.
//  * Phase 1 remapped to 4 lanes/row (192 rows/iter, 6 iters): lane q of
//    a row-quad loads W bytes [64k+16q) (k=0..7; 4 lanes = 1 line/row
//    -> 16 lines/instr, keeps r2's TA fix), computes 8 half-dots,
//    qpadd1 completes, keeps the 4 with k-parity q&1: o = 4j+off,
//    off = 2(q&1)+(q>>1). These 4 (x2 g) ARE this thread's phase-2
//    ownership set -> stash in regs as packed bf16 (st[6][2][2], 24
//    VGPRs, static-indexed, pass loop UNROLLED so no spill across
//    back-edge — r7's pv[12] lesson).
//  * Phase 2: no g-split (each thread: 6 rows x both g = same work),
//    ZERO ds_read in the hot loop; only wsum scalar reads per pass.
//  * Dynamic LDS 73.7KB -> 0; occupancy now thread/VGPR-limited only
//    (2 blocks/CU needs VGPR<=85 -> launch_bounds(768,6)).
//  * r8's XCD swizzle REVERTED (FETCH doubled, dur nil: W was already
//    L2-resident under c-major order).
// Same dot association + same cvtpk RNE grid as r8 -> absmax identical.
#define BB 256
#define RR 1152
#define CC 10
#define OO 16
#define II 8
#define NT 768
#define GG 2
#define NWAVE (NT / 64)    // 12
#define LOG2E 1.4426950408889634f

typedef float float2v __attribute__((ext_vector_type(2)));

__device__ __forceinline__ void unpack2(uint32_t pk, float& lo, float& hi) {
    union { uint32_t i; float f; } a, b;
    a.i = pk << 16; b.i = pk & 0xffff0000u;
    lo = a.f; hi = b.f;
}
// dot4 via packed f32: pk_mul + pk_fma + hadd (same association as r7/r8)
__device__ __forceinline__ float dot4pk(float4 a, float4 b) {
    float2v al = { a.x, a.y }, ah = { a.z, a.w };
    float2v bl = { b.x, b.y }, bh = { b.z, b.w };
    float2v h = __builtin_elementwise_fma(ah, bh, al * bl);
    return h.x + h.y;
}
// v + (value from lane l^1), DPP quad_perm [1,0,3,2] — VALU pipe
__device__ __forceinline__ float qpadd1(float v) {
    int o = __builtin_amdgcn_mov_dpp(__float_as_int(v), 0xB1, 0xF, 0xF, true);
    return v + __int_as_float(o);
}
// v + (value from lane l^2), DPP quad_perm [2,3,0,1]
__device__ __forceinline__ float qpadd2(float v) {
    int o = __builtin_amdgcn_mov_dpp(__float_as_int(v), 0x4E, 0xF, 0xF, true);
    return v + __int_as_float(o);
}
// packed bf16 pair from two f32 (hardware RNE), one instruction
__device__ __forceinline__ uint32_t cvtpk(float lo, float hi) {
    uint32_t r;
    asm("v_cvt_pk_bf16_f32 %0, %1, %2" : "=v"(r) : "v"(lo), "v"(hi));
    return r;
}
#if __has_builtin(__builtin_amdgcn_exp2f)
#define EXP2(x) __builtin_amdgcn_exp2f(x)
#else
#define EXP2(x) __expf((x) * 0.6931471805599453f)
#endif

__global__ __launch_bounds__(NT, 6)   // VGPR cap 85: 2 blocks/CU (24 waves)
void k_caps(const float* __restrict__ x, const float* __restrict__ W,
            float* __restrict__ out) {
    __shared__ float part[NWAVE][GG][18];     // [wv][g][o 0..15, den at 16]
    __shared__ float p0s[NWAVE][4][4][GG];    // [wv][q][j][g]
    __shared__ float wsum[GG][OO];

    const int t = threadIdx.x;
    const int c  = blockIdx.x / (BB / GG);    // c-major: blocks share W-slice
    const int b0 = (blockIdx.x % (BB / GG)) * GG;
    const int wv = t >> 6, l = t & 63;
    const int q = l & 3, rl = l >> 2;         // quad lane / row-in-wave
    const int r0 = wv * 16 + rl;              // + 192 per iter
    const int off = 2 * (q & 1) + (q >> 1);   // lane owns o = 4j + off
    const bool qb = (q & 1) != 0;

    // register-resident u: [iter][g][pair], packed bf16 (d0,d1)(d2,d3)
    uint32_t st[6][GG][2];
    float s00 = 0.f, s01 = 0.f, s02 = 0.f, s03 = 0.f;
    float s10 = 0.f, s11 = 0.f, s12 = 0.f, s13 = 0.f;

    const float* wb  = W + ((size_t)r0 * CC + c) * (OO * II) + 4 * q;
    const float* xb0 = x + ((size_t)b0 * RR + r0) * II + 4 * (q & 1);
    const float* xb1 = xb0 + (size_t)RR * II;

    // ---- Phase 1: per iter, lane's 8 W-float4 cover o=2k+(q>>1), i-half q&1
#pragma unroll
    for (int it = 0; it < 6; ++it) {
        const float* wp = wb + (size_t)it * (192 * CC * OO * II);
        float4 w0 = *reinterpret_cast<const float4*>(wp);
        float4 w1 = *reinterpret_cast<const float4*>(wp + 16);
        float4 w2 = *reinterpret_cast<const float4*>(wp + 32);
        float4 w3 = *reinterpret_cast<const float4*>(wp + 48);
        float4 w4 = *reinterpret_cast<const float4*>(wp + 64);
        float4 w5 = *reinterpret_cast<const float4*>(wp + 80);
        float4 w6 = *reinterpret_cast<const float4*>(wp + 96);
        float4 w7 = *reinterpret_cast<const float4*>(wp + 112);
        float4 xa = *reinterpret_cast<const float4*>(xb0 + (size_t)it * 192 * II);
        float4 xc = *reinterpret_cast<const float4*>(xb1 + (size_t)it * 192 * II);
        // ---- g = 0 ----
        {
            float f0 = qpadd1(dot4pk(w0, xa));
            float f1 = qpadd1(dot4pk(w1, xa));
            float f2 = qpadd1(dot4pk(w2, xa));
            float f3 = qpadd1(dot4pk(w3, xa));
            float f4 = qpadd1(dot4pk(w4, xa));
            float f5 = qpadd1(dot4pk(w5, xa));
            float f6 = qpadd1(dot4pk(w6, xa));
            float f7 = qpadd1(dot4pk(w7, xa));
            float d0 = qb ? f1 : f0, d1 = qb ? f3 : f2;
            float d2 = qb ? f5 : f4, d3 = qb ? f7 : f6;
            s00 += d0; s01 += d1; s02 += d2; s03 += d3;
            st[it][0][0] = cvtpk(d0, d1);
            st[it][0][1] = cvtpk(d2, d3);
        }
        // ---- g = 1 ----
        {
            float f0 = qpadd1(dot4pk(w0, xc));
            float f1 = qpadd1(dot4pk(w1, xc));
            float f2 = qpadd1(dot4pk(w2, xc));
            float f3 = qpadd1(dot4pk(w3, xc));
            float f4 = qpadd1(dot4pk(w4, xc));
            float f5 = qpadd1(dot4pk(w5, xc));
            float f6 = qpadd1(dot4pk(w6, xc));
            float f7 = qpadd1(dot4pk(w7, xc));
            float d0 = qb ? f1 : f0, d1 = qb ? f3 : f2;
            float d2 = qb ? f5 : f4, d3 = qb ? f7 : f6;
            s10 += d0; s11 += d1; s12 += d2; s13 += d3;
            st[it][1][0] = cvtpk(d0, d1);
            st[it][1][1] = cvtpk(d2, d3);
        }
    }
    // pass-0 reduce: 16 same-q lanes hold distinct rows (masks 4,8,16,32)
#pragma unroll
    for (int m = 4; m < 64; m <<= 1) {
        s00 += __shfl_xor(s00, m); s01 += __shfl_xor(s01, m);
        s02 += __shfl_xor(s02, m); s03 += __shfl_xor(s03, m);
        s10 += __shfl_xor(s10, m); s11 += __shfl_xor(s11, m);
        s12 += __shfl_xor(s12, m); s13 += __shfl_xor(s13, m);
    }
    if (l < 4) {                              // lane l == q
        p0s[wv][l][0][0] = s00; p0s[wv][l][1][0] = s01;
        p0s[wv][l][2][0] = s02; p0s[wv][l][3][0] = s03;
        p0s[wv][l][0][1] = s10; p0s[wv][l][1][1] = s11;
        p0s[wv][l][2][1] = s12; p0s[wv][l][3][1] = s13;
    }
    __syncthreads();

    if (t < GG * OO) {   // g = t>>4, o = t&15 (wave 0)
        const int g = t >> 4, o = t & 15;
        const int rem = o & 3;
        const int qo = (rem >> 1) + 2 * (rem & 1);   // owner lane of o
        const int jo = o >> 2;
        float s = 0.f;
#pragma unroll
        for (int w = 0; w < NWAVE; ++w) s += p0s[w][qo][jo][g];
        s *= (1.0f / RR);                     // softmax(0) = 1/R
        float ss = s * s;                     // squash over 16-lane o-group
        ss += __shfl_xor(ss, 1); ss += __shfl_xor(ss, 2);
        ss += __shfl_xor(ss, 4); ss += __shfl_xor(ss, 8);
        wsum[g][o] = s * (ss / ((1.0f + ss) * sqrtf(ss + 1e-7f)));  // v0
    }
    __syncthreads();

    // ---- Phase 2: both passes straight-line (stash must not cross a
    //      loop back-edge with barriers — r7 spill lesson) ----
#pragma unroll
    for (int pass = 1; pass < 3; ++pass) {
        // routing weights for this lane's o-set, pre-scaled by log2(e)
        float wq00 = wsum[0][off]      * LOG2E, wq01 = wsum[0][4 + off] * LOG2E;
        float wq02 = wsum[0][8 + off]  * LOG2E, wq03 = wsum[0][12 + off] * LOG2E;
        float wq10 = wsum[1][off]      * LOG2E, wq11 = wsum[1][4 + off] * LOG2E;
        float wq12 = wsum[1][8 + off]  * LOG2E, wq13 = wsum[1][12 + off] * LOG2E;
        float n00 = 0.f, n01 = 0.f, n02 = 0.f, n03 = 0.f;
        float n10 = 0.f, n11 = 0.f, n12 = 0.f, n13 = 0.f;
        float den0 = 0.f, den1 = 0.f;

#pragma unroll
        for (int it = 0; it < 6; ++it) {
            // ---- g = 0 ----
            {
                float u0, u1, u2, u3;
                unpack2(st[it][0][0], u0, u1);
                unpack2(st[it][0][1], u2, u3);
                float lg = u0 * wq00;
                lg = fmaf(u1, wq01, lg);
                lg = fmaf(u2, wq02, lg);
                lg = fmaf(u3, wq03, lg);
                lg = qpadd1(lg);              // + partner o-set (quad)
                lg = qpadd2(lg);              // full 16-o logit
                float e = EXP2(lg);           // == exp(raw logit)
                den0 += e;
                n00 = fmaf(e, u0, n00); n01 = fmaf(e, u1, n01);
                n02 = fmaf(e, u2, n02); n03 = fmaf(e, u3, n03);
            }
            // ---- g = 1 ----
            {
                float u0, u1, u2, u3;
                unpack2(st[it][1][0], u0, u1);
                unpack2(st[it][1][1], u2, u3);
                float lg = u0 * wq10;
                lg = fmaf(u1, wq11, lg);
                lg = fmaf(u2, wq12, lg);
                lg = fmaf(u3, wq13, lg);
                lg = qpadd1(lg);
                lg = qpadd2(lg);
                float e = EXP2(lg);
                den1 += e;
                n10 = fmaf(e, u0, n10); n11 = fmaf(e, u1, n11);
                n12 = fmaf(e, u2, n12); n13 = fmaf(e, u3, n13);
            }
        }

#pragma unroll
        for (int m = 4; m < 64; m <<= 1) {    // 16 same-q lanes: distinct rows
            n00 += __shfl_xor(n00, m); n01 += __shfl_xor(n01, m);
            n02 += __shfl_xor(n02, m); n03 += __shfl_xor(n03, m);
            n10 += __shfl_xor(n10, m); n11 += __shfl_xor(n11, m);
            n12 += __shfl_xor(n12, m); n13 += __shfl_xor(n13, m);
            den0 += __shfl_xor(den0, m); den1 += __shfl_xor(den1, m);
        }
        if (l < 4) {                          // lane l == q; off is lane's own
            part[wv][0][off]      = n00; part[wv][0][4 + off]  = n01;
            part[wv][0][8 + off]  = n02; part[wv][0][12 + off] = n03;
            part[wv][1][off]      = n10; part[wv][1][4 + off]  = n11;
            part[wv][1][8 + off]  = n12; part[wv][1][12 + off] = n13;
            if (l == 0) { part[wv][0][16] = den0; part[wv][1][16] = den1; }
        }
        __syncthreads();

        if (t < GG * OO) {
            const int g = t >> 4, o = t & 15;
            float nf = 0.f, df = 0.f;
#pragma unroll
            for (int w = 0; w < NWAVE; ++w) {
                nf += part[w][g][o];
                df += part[w][g][16];
            }
            float s = nf / df;
            float ss = s * s;
            ss += __shfl_xor(ss, 1); ss += __shfl_xor(ss, 2);
            ss += __shfl_xor(ss, 4); ss += __shfl_xor(ss, 8);
            float v = s * (ss / ((1.0f + ss) * sqrtf(ss + 1e-7f)));
            if (pass == 2)
                out[((size_t)(b0 + g) * CC + c) * OO + o] = v;
            else
                wsum[g][o] += v;
        }
        __syncthreads();
    }
}

extern "C" void kernel_launch(void* const* d_in, const int* in_sizes, int n_in,
                              void* d_out, int out_size, void* d_ws, size_t ws_size,
                              hipStream_t stream) {
    const float* x = (const float*)d_in[0];  // (B,R,I) fp32
    const float* W = (const float*)d_in[1];  // (R,C,O,I) fp32
    if (n_in >= 2 && in_sizes[0] == RR * CC * OO * II &&
        in_sizes[1] == BB * RR * II) {
        const float* tmp = x; x = W; W = tmp;
    }
    float* out = (float*)d_out;              // (B,1,C,O,1) fp32

    k_caps<<<CC * (BB / GG), NT, 0, stream>>>(x, W, out);
}

// Round 10
// 108.419 us; speedup vs baseline: 1.1389x; 1.1389x over previous
//
#include <hip/hip_runtime.h>
#include <cstdint>

// CapsuleLayer dynamic routing: B=256, R=1152, C=10, O=16, I=8, 3 iters.
// Round 10: register-resident u via NAMED SCALARS (not arrays).
//  * r7 (pv[12]) and r9 (st[6][2][2]) both proved: a C array whose live
//    range crosses __syncthreads() is demoted to scratch by this compiler
//    even with static indices (VGPR=40 yet 15-58MB scratch traffic).
//    Named uint32_t scalars are SSA values - regalloc must register them.
//  * Structure = r9: 4 lanes/row phase 1 (lane q loads W[64k+16q],
//    8 half-dots, qpadd1 completes, keeps 4 by k-parity q&1 ->
//    o = 4j + off, off=2(q&1)+(q>>1)); stash 6 iters x 2 g x 2 packed
//    bf16 words = 24 named VGPRs. Phase 2 reads stash only: ZERO ds
//    ops for u, ZERO dynamic LDS.
//  * Phase-1 iteration processes W in two 4xfloat4 halves to cap live
//    W-regs at 16. No explicit prefetch (r8: spill trigger). No XCD
//    swizzle (r8: falsified). pk-math diet + exp2 fold kept.
// Same dot association + cvtpk RNE grid as r9 -> absmax identical.
#define BB 256
#define RR 1152
#define CC 10
#define OO 16
#define II 8
#define NT 768
#define GG 2
#define NWAVE (NT / 64)    // 12
#define LOG2E 1.4426950408889634f

typedef float float2v __attribute__((ext_vector_type(2)));

__device__ __forceinline__ void unpack2(uint32_t pk, float& lo, float& hi) {
    union { uint32_t i; float f; } a, b;
    a.i = pk << 16; b.i = pk & 0xffff0000u;
    lo = a.f; hi = b.f;
}
// dot4 via packed f32: pk_mul + pk_fma + hadd (same association as r7-r9)
__device__ __forceinline__ float dot4pk(float4 a, float4 b) {
    float2v al = { a.x, a.y }, ah = { a.z, a.w };
    float2v bl = { b.x, b.y }, bh = { b.z, b.w };
    float2v h = __builtin_elementwise_fma(ah, bh, al * bl);
    return h.x + h.y;
}
// v + (value from lane l^1), DPP quad_perm [1,0,3,2] — VALU pipe
__device__ __forceinline__ float qpadd1(float v) {
    int o = __builtin_amdgcn_mov_dpp(__float_as_int(v), 0xB1, 0xF, 0xF, true);
    return v + __int_as_float(o);
}
// v + (value from lane l^2), DPP quad_perm [2,3,0,1]
__device__ __forceinline__ float qpadd2(float v) {
    int o = __builtin_amdgcn_mov_dpp(__float_as_int(v), 0x4E, 0xF, 0xF, true);
    return v + __int_as_float(o);
}
// packed bf16 pair from two f32 (hardware RNE), one instruction
__device__ __forceinline__ uint32_t cvtpk(float lo, float hi) {
    uint32_t r;
    asm("v_cvt_pk_bf16_f32 %0, %1, %2" : "=v"(r) : "v"(lo), "v"(hi));
    return r;
}
#if __has_builtin(__builtin_amdgcn_exp2f)
#define EXP2(x) __builtin_amdgcn_exp2f(x)
#else
#define EXP2(x) __expf((x) * 0.6931471805599453f)
#endif

#define LD4(P) (*reinterpret_cast<const float4*>(P))

// one phase-1 iteration: fills stash words AW0,AW1 (g=0) / BW0,BW1 (g=1)
#define P1_ITER(IT, AW0, AW1, BW0, BW1)                                       \
  do {                                                                        \
    const float* wp  = wb  + (size_t)(IT) * (192 * CC * OO * II);             \
    float4 xa = LD4(xb0 + (size_t)(IT) * 192 * II);                           \
    float4 xc = LD4(xb1 + (size_t)(IT) * 192 * II);                           \
    {                                                                         \
      float4 w0 = LD4(wp), w1 = LD4(wp + 16), w2 = LD4(wp + 32),              \
             w3 = LD4(wp + 48);                                               \
      float f0 = qpadd1(dot4pk(w0, xa)), f1 = qpadd1(dot4pk(w1, xa));         \
      float f2 = qpadd1(dot4pk(w2, xa)), f3 = qpadd1(dot4pk(w3, xa));         \
      float h0 = qpadd1(dot4pk(w0, xc)), h1 = qpadd1(dot4pk(w1, xc));         \
      float h2 = qpadd1(dot4pk(w2, xc)), h3 = qpadd1(dot4pk(w3, xc));         \
      float d0 = qb ? f1 : f0, d1 = qb ? f3 : f2;                             \
      s00 += d0; s01 += d1; AW0 = cvtpk(d0, d1);                              \
      float e0 = qb ? h1 : h0, e1 = qb ? h3 : h2;                             \
      s10 += e0; s11 += e1; BW0 = cvtpk(e0, e1);                              \
    }                                                                         \
    {                                                                         \
      float4 w4 = LD4(wp + 64), w5 = LD4(wp + 80), w6 = LD4(wp + 96),         \
             w7 = LD4(wp + 112);                                              \
      float f4 = qpadd1(dot4pk(w4, xa)), f5 = qpadd1(dot4pk(w5, xa));         \
      float f6 = qpadd1(dot4pk(w6, xa)), f7 = qpadd1(dot4pk(w7, xa));         \
      float h4 = qpadd1(dot4pk(w4, xc)), h5 = qpadd1(dot4pk(w5, xc));         \
      float h6 = qpadd1(dot4pk(w6, xc)), h7 = qpadd1(dot4pk(w7, xc));         \
      float d2 = qb ? f5 : f4, d3 = qb ? f7 : f6;                             \
      s02 += d2; s03 += d3; AW1 = cvtpk(d2, d3);                              \
      float e2 = qb ? h5 : h4, e3 = qb ? h7 : h6;                             \
      s12 += e2; s13 += e3; BW1 = cvtpk(e2, e3);                              \
    }                                                                         \
  } while (0)

// one phase-2 row-g contribution from stash words W0,W1
#define P2_ROW(W0, W1, DEN, NA, NB, WQA, WQB)                                 \
  do {                                                                        \
    float u0, u1, u2, u3;                                                     \
    unpack2(W0, u0, u1); unpack2(W1, u2, u3);                                 \
    float2v P0 = { u0, u2 }, P1 = { u1, u3 };                                 \
    float2v lg2 = __builtin_elementwise_fma(P0, WQA, P1 * WQB);               \
    float lg = lg2.x + lg2.y;                                                 \
    lg = qpadd1(lg);                                                          \
    lg = qpadd2(lg);                                                          \
    float e = EXP2(lg);                                                       \
    DEN += e;                                                                 \
    float2v E2 = { e, e };                                                    \
    NA = __builtin_elementwise_fma(E2, P0, NA);                               \
    NB = __builtin_elementwise_fma(E2, P1, NB);                               \
  } while (0)

__global__ __launch_bounds__(NT, 6)   // VGPR cap 85: 2 blocks/CU (24 waves)
void k_caps(const float* __restrict__ x, const float* __restrict__ W,
            float* __restrict__ out) {
    __shared__ float part[NWAVE][GG][18];     // [wv][g][o 0..15, den at 16]
    __shared__ float p0s[NWAVE][4][4][GG];    // [wv][q][j][g]
    __shared__ float wsum[GG][OO];

    const int t = threadIdx.x;
    const int c  = blockIdx.x / (BB / GG);    // c-major: blocks share W-slice
    const int b0 = (blockIdx.x % (BB / GG)) * GG;
    const int wv = t >> 6, l = t & 63;
    const int q = l & 3, rl = l >> 2;         // quad lane / row-in-wave
    const int r0 = wv * 16 + rl;              // + 192 per iter
    const int off = 2 * (q & 1) + (q >> 1);   // lane owns o = 4j + off
    const bool qb = (q & 1) != 0;

    const float* wb  = W + ((size_t)r0 * CC + c) * (OO * II) + 4 * q;
    const float* xb0 = x + ((size_t)b0 * RR + r0) * II + 4 * (q & 1);
    const float* xb1 = xb0 + (size_t)RR * II;

    // register-resident u stash: 24 NAMED scalars (packed bf16 pairs)
    uint32_t A00, A01, A10, A11, A20, A21, A30, A31, A40, A41, A50, A51;
    uint32_t B00, B01, B10, B11, B20, B21, B30, B31, B40, B41, B50, B51;
    float s00 = 0.f, s01 = 0.f, s02 = 0.f, s03 = 0.f;
    float s10 = 0.f, s11 = 0.f, s12 = 0.f, s13 = 0.f;

    // ---- Phase 1 (straight-line) ----
    P1_ITER(0, A00, A01, B00, B01);
    P1_ITER(1, A10, A11, B10, B11);
    P1_ITER(2, A20, A21, B20, B21);
    P1_ITER(3, A30, A31, B30, B31);
    P1_ITER(4, A40, A41, B40, B41);
    P1_ITER(5, A50, A51, B50, B51);

    // pass-0 reduce: 16 same-q lanes hold distinct rows (masks 4,8,16,32)
#pragma unroll
    for (int m = 4; m < 64; m <<= 1) {
        s00 += __shfl_xor(s00, m); s01 += __shfl_xor(s01, m);
        s02 += __shfl_xor(s02, m); s03 += __shfl_xor(s03, m);
        s10 += __shfl_xor(s10, m); s11 += __shfl_xor(s11, m);
        s12 += __shfl_xor(s12, m); s13 += __shfl_xor(s13, m);
    }
    if (l < 4) {                              // lane l == q
        p0s[wv][l][0][0] = s00; p0s[wv][l][1][0] = s01;
        p0s[wv][l][2][0] = s02; p0s[wv][l][3][0] = s03;
        p0s[wv][l][0][1] = s10; p0s[wv][l][1][1] = s11;
        p0s[wv][l][2][1] = s12; p0s[wv][l][3][1] = s13;
    }
    __syncthreads();

    if (t < GG * OO) {   // g = t>>4, o = t&15 (wave 0)
        const int g = t >> 4, o = t & 15;
        const int rem = o & 3;
        const int qo = (rem >> 1) + 2 * (rem & 1);   // owner lane of o
        const int jo = o >> 2;
        float s = 0.f;
#pragma unroll
        for (int w = 0; w < NWAVE; ++w) s += p0s[w][qo][jo][g];
        s *= (1.0f / RR);                     // softmax(0) = 1/R
        float ss = s * s;                     // squash over 16-lane o-group
        ss += __shfl_xor(ss, 1); ss += __shfl_xor(ss, 2);
        ss += __shfl_xor(ss, 4); ss += __shfl_xor(ss, 8);
        wsum[g][o] = s * (ss / ((1.0f + ss) * sqrtf(ss + 1e-7f)));  // v0
    }
    __syncthreads();

    // ---- Phase 2: both passes from the register stash ----
#pragma unroll
    for (int pass = 1; pass < 3; ++pass) {
        // lane's routing weights, pre-scaled by log2(e): P0 pairs (j0,j2),
        // P1 pairs (j1,j3) -> WQA = (w[off], w[8+off]), WQB = (w[4+off], w[12+off])
        const float2v WA0 = { wsum[0][off] * LOG2E,      wsum[0][8 + off] * LOG2E };
        const float2v WB0 = { wsum[0][4 + off] * LOG2E,  wsum[0][12 + off] * LOG2E };
        const float2v WA1 = { wsum[1][off] * LOG2E,      wsum[1][8 + off] * LOG2E };
        const float2v WB1 = { wsum[1][4 + off] * LOG2E,  wsum[1][12 + off] * LOG2E };
        float2v NA0 = { 0.f, 0.f }, NB0 = { 0.f, 0.f };
        float2v NA1 = { 0.f, 0.f }, NB1 = { 0.f, 0.f };
        float den0 = 0.f, den1 = 0.f;

        P2_ROW(A00, A01, den0, NA0, NB0, WA0, WB0);
        P2_ROW(B00, B01, den1, NA1, NB1, WA1, WB1);
        P2_ROW(A10, A11, den0, NA0, NB0, WA0, WB0);
        P2_ROW(B10, B11, den1, NA1, NB1, WA1, WB1);
        P2_ROW(A20, A21, den0, NA0, NB0, WA0, WB0);
        P2_ROW(B20, B21, den1, NA1, NB1, WA1, WB1);
        P2_ROW(A30, A31, den0, NA0, NB0, WA0, WB0);
        P2_ROW(B30, B31, den1, NA1, NB1, WA1, WB1);
        P2_ROW(A40, A41, den0, NA0, NB0, WA0, WB0);
        P2_ROW(B40, B41, den1, NA1, NB1, WA1, WB1);
        P2_ROW(A50, A51, den0, NA0, NB0, WA0, WB0);
        P2_ROW(B50, B51, den1, NA1, NB1, WA1, WB1);

        float n00 = NA0.x, n01 = NB0.x, n02 = NA0.y, n03 = NB0.y;
        float n10 = NA1.x, n11 = NB1.x, n12 = NA1.y, n13 = NB1.y;
#pragma unroll
        for (int m = 4; m < 64; m <<= 1) {    // 16 same-q lanes: distinct rows
            n00 += __shfl_xor(n00, m); n01 += __shfl_xor(n01, m);
            n02 += __shfl_xor(n02, m); n03 += __shfl_xor(n03, m);
            n10 += __shfl_xor(n10, m); n11 += __shfl_xor(n11, m);
            n12 += __shfl_xor(n12, m); n13 += __shfl_xor(n13, m);
            den0 += __shfl_xor(den0, m); den1 += __shfl_xor(den1, m);
        }
        if (l < 4) {                          // lane l == q; off is lane's own
            part[wv][0][off]      = n00; part[wv][0][4 + off]  = n01;
            part[wv][0][8 + off]  = n02; part[wv][0][12 + off] = n03;
            part[wv][1][off]      = n10; part[wv][1][4 + off]  = n11;
            part[wv][1][8 + off]  = n12; part[wv][1][12 + off] = n13;
            if (l == 0) { part[wv][0][16] = den0; part[wv][1][16] = den1; }
        }
        __syncthreads();

        if (t < GG * OO) {
            const int g = t >> 4, o = t & 15;
            float nf = 0.f, df = 0.f;
#pragma unroll
            for (int w = 0; w < NWAVE; ++w) {
                nf += part[w][g][o];
                df += part[w][g][16];
            }
            float s = nf / df;
            float ss = s * s;
            ss += __shfl_xor(ss, 1); ss += __shfl_xor(ss, 2);
            ss += __shfl_xor(ss, 4); ss += __shfl_xor(ss, 8);
            float v = s * (ss / ((1.0f + ss) * sqrtf(ss + 1e-7f)));
            if (pass == 2)
                out[((size_t)(b0 + g) * CC + c) * OO + o] = v;
            else
                wsum[g][o] += v;
        }
        __syncthreads();
    }
}

extern "C" void kernel_launch(void* const* d_in, const int* in_sizes, int n_in,
                              void* d_out, int out_size, void* d_ws, size_t ws_size,
                              hipStream_t stream) {
    const float* x = (const float*)d_in[0];  // (B,R,I) fp32
    const float* W = (const float*)d_in[1];  // (R,C,O,I) fp32
    if (n_in >= 2 && in_sizes[0] == RR * CC * OO * II &&
        in_sizes[1] == BB * RR * II) {
        const float* tmp = x; x = W; W = tmp;
    }
    float* out = (float*)d_out;              // (B,1,C,O,1) fp32

    k_caps<<<CC * (BB / GG), NT, 0, stream>>>(x, W, out);
}